// Round 3
// baseline (548.612 us; speedup 1.0000x reference)
//
#include <hip/hip_runtime.h>
#include <stdint.h>

// Shapes (fixed): B=512, N=128, E=128, H=4, D=512, hd=128.

typedef __attribute__((ext_vector_type(8))) __bf16 bf16x8;
typedef __attribute__((ext_vector_type(8))) uint16_t u16x8;
typedef __attribute__((ext_vector_type(4))) float f32x4;

__device__ __forceinline__ float b2f(uint16_t h) {
  union { uint32_t u; float f; } c; c.u = ((uint32_t)h) << 16; return c.f;
}
__device__ __forceinline__ uint16_t f2b(float f) {
  union { float f; uint32_t u; } c; c.f = f;
  return (uint16_t)((c.u + 0x7fffu + ((c.u >> 16) & 1u)) >> 16);
}
__device__ __forceinline__ void gld16(void* lds, const void* g) {
  __builtin_amdgcn_global_load_lds(
      (const __attribute__((address_space(1))) uint32_t*)(g),
      (__attribute__((address_space(3))) uint32_t*)(lds),
      16, 0, 0);
}
__device__ __forceinline__ void stc(float* C, size_t i, float v) { C[i] = v; }
__device__ __forceinline__ void stc(uint16_t* C, size_t i, float v) { C[i] = f2b(v); }

#define MFMA16(a, b, c) __builtin_amdgcn_mfma_f32_16x16x32_bf16((a), (b), (c), 0, 0, 0)

// ---------------- pack f32 -> bf16 (4 elems/thread) ----------------
__global__ __launch_bounds__(256) void pack_bf16(const float* __restrict__ in,
                                                 uint16_t* __restrict__ out, int n4) {
  int i = blockIdx.x * 256 + threadIdx.x;
  if (i >= n4) return;
  float4 v = ((const float4*)in)[i];
  ushort4 o;
  o.x = f2b(v.x); o.y = f2b(v.y); o.z = f2b(v.z); o.w = f2b(v.w);
  ((ushort4*)out)[i] = o;
}

// ---------------- bqc[i] = b2[i] + sum_k Wbig[i,k]*b1[k]  (512x512, f32) ----------------
__global__ __launch_bounds__(256) void combine_bias(const float* __restrict__ Wbig,
                                                    const float* __restrict__ b1,
                                                    const float* __restrict__ b2,
                                                    float* __restrict__ out) {
  const int t = threadIdx.x, l = t & 63, w = t >> 6;
  const int row = blockIdx.x * 4 + w;
  float s = 0.f;
  #pragma unroll
  for (int j = 0; j < 8; ++j) {
    int c = j * 64 + l;
    s += Wbig[(size_t)row * 512 + c] * b1[c];
  }
  #pragma unroll
  for (int m = 1; m < 64; m <<= 1) s += __shfl_xor(s, m);
  if (l == 0) out[row] = s + b2[row];
}

// ---------------- C(MxN) = A(MxK) @ W(NxK)^T + bias ; 128x128 tile, BK=64 ----------------
template <typename OT>
__global__ __launch_bounds__(256) void gemm_bt_kernel(
    const uint16_t* __restrict__ A, const uint16_t* __restrict__ W,
    const float* __restrict__ bias, OT* __restrict__ C, int N, int K) {
  __shared__ uint16_t As[128 * 64];
  __shared__ uint16_t Bs[128 * 64];
  const int t = threadIdx.x, l = t & 63, w = t >> 6;
  const int wr = w >> 1, wc = w & 1, l15 = l & 15, hi = l >> 4;
  const int mtile = blockIdx.y, ntile = blockIdx.x;
  f32x4 acc[4][4];
  #pragma unroll
  for (int m = 0; m < 4; ++m)
    #pragma unroll
    for (int n = 0; n < 4; ++n) acc[m][n] = (f32x4){0.f, 0.f, 0.f, 0.f};
  const int srow = t >> 3, schunk = (t & 7) * 8;
  const int nk = K >> 6;
  const int rowA0 = mtile * 128, rowB0 = ntile * 128;
  for (int kt = 0; kt < nk; ++kt) {
    const int kb = kt << 6;
    #pragma unroll
    for (int i = 0; i < 4; ++i) {
      const int r = i * 32 + srow;
      gld16(&As[r * 64 + schunk], A + (size_t)(rowA0 + r) * K + kb + schunk);
      gld16(&Bs[r * 64 + schunk], W + (size_t)(rowB0 + r) * K + kb + schunk);
    }
    __syncthreads();
    #pragma unroll
    for (int ks = 0; ks < 2; ++ks) {
      const int k0 = ks * 32 + hi * 8;
      bf16x8 a[4], bb[4];
      #pragma unroll
      for (int m = 0; m < 4; ++m) a[m] = *(const bf16x8*)&As[(wr * 64 + m * 16 + l15) * 64 + k0];
      #pragma unroll
      for (int n = 0; n < 4; ++n) bb[n] = *(const bf16x8*)&Bs[(wc * 64 + n * 16 + l15) * 64 + k0];
      #pragma unroll
      for (int m = 0; m < 4; ++m)
        #pragma unroll
        for (int n = 0; n < 4; ++n) acc[m][n] = MFMA16(a[m], bb[n], acc[m][n]);
    }
    __syncthreads();
  }
  #pragma unroll
  for (int m = 0; m < 4; ++m) {
    const int row = rowA0 + wr * 64 + m * 16 + hi * 4;
    #pragma unroll
    for (int n = 0; n < 4; ++n) {
      const int col = rowB0 + wc * 64 + n * 16 + l15;
      const float bv = bias[col];
      #pragma unroll
      for (int r = 0; r < 4; ++r)
        stc(C, (size_t)(row + r) * N + col, acc[m][n][r] + bv);
    }
  }
}

// ---------------- C = A(MxK) @ B(KxN), B row-major (transpose-staged), bf16 out, batched ----
__global__ __launch_bounds__(256) void gemm_ab_kernel(
    const uint16_t* __restrict__ A, int lda, long long sA,
    const uint16_t* __restrict__ B, int ldb, long long sB,
    uint16_t* __restrict__ C, int ldc, long long sC, int K) {
  __shared__ uint16_t As[128 * 64];
  __shared__ uint16_t Bt[128 * 64];  // [n][k]
  const int t = threadIdx.x, l = t & 63, w = t >> 6;
  const int wr = w >> 1, wc = w & 1, l15 = l & 15, hi = l >> 4;
  const int mtile = blockIdx.y, ntile = blockIdx.x, bz = blockIdx.z;
  const uint16_t* Ab = A + (size_t)bz * sA;
  const uint16_t* Bb = B + (size_t)bz * sB;
  uint16_t* Cb = C + (size_t)bz * sC;
  f32x4 acc[4][4];
  #pragma unroll
  for (int m = 0; m < 4; ++m)
    #pragma unroll
    for (int n = 0; n < 4; ++n) acc[m][n] = (f32x4){0.f, 0.f, 0.f, 0.f};
  const int srow = t >> 3, schunk = (t & 7) * 8;
  const int nk = K >> 6;
  for (int kt = 0; kt < nk; ++kt) {
    const int kb = kt << 6;
    #pragma unroll
    for (int i = 0; i < 4; ++i) {
      const int r = i * 32 + srow;
      gld16(&As[r * 64 + schunk], Ab + (size_t)(mtile * 128 + r) * lda + kb + schunk);
    }
    #pragma unroll
    for (int rd = 0; rd < 4; ++rd) {
      const int id = rd * 256 + t;
      const int kr = id >> 4;
      const int c = (id & 15) * 8;
      u16x8 gv = *(const u16x8*)(Bb + (size_t)(kb + kr) * ldb + ntile * 128 + c);
      #pragma unroll
      for (int j = 0; j < 8; ++j) Bt[(c + j) * 64 + kr] = gv[j];
    }
    __syncthreads();
    #pragma unroll
    for (int ks = 0; ks < 2; ++ks) {
      const int k0 = ks * 32 + hi * 8;
      bf16x8 a[4], bb[4];
      #pragma unroll
      for (int m = 0; m < 4; ++m) a[m] = *(const bf16x8*)&As[(wr * 64 + m * 16 + l15) * 64 + k0];
      #pragma unroll
      for (int n = 0; n < 4; ++n) bb[n] = *(const bf16x8*)&Bt[(wc * 64 + n * 16 + l15) * 64 + k0];
      #pragma unroll
      for (int m = 0; m < 4; ++m)
        #pragma unroll
        for (int n = 0; n < 4; ++n) acc[m][n] = MFMA16(a[m], bb[n], acc[m][n]);
    }
    __syncthreads();
  }
  #pragma unroll
  for (int m = 0; m < 4; ++m) {
    const int row = mtile * 128 + wr * 64 + m * 16 + hi * 4;
    #pragma unroll
    for (int n = 0; n < 4; ++n) {
      const int col = ntile * 128 + wc * 64 + n * 16 + l15;
      #pragma unroll
      for (int r = 0; r < 4; ++r)
        Cb[(size_t)(row + r) * ldc + col] = f2b(acc[m][n][r]);
    }
  }
}

// ---------------- pad flags: -inf where row of xe is all-zero ----------------
__global__ __launch_bounds__(256) void pad_kernel(const uint16_t* __restrict__ xe,
                                                  float* __restrict__ padadd) {
  const int t = threadIdx.x, l = t & 63, w = t >> 6;
  const size_t row = (size_t)blockIdx.x * 4 + w;
  u16x8 v = *(const u16x8*)(xe + row * 512 + l * 8);
  float s = 0.f;
  #pragma unroll
  for (int j = 0; j < 8; ++j) s += fabsf(b2f(v[j]));
  #pragma unroll
  for (int m = 1; m < 64; m <<= 1) s += __shfl_xor(s, m);
  if (l == 0) padadd[row] = (s == 0.f) ? -__builtin_inff() : 0.f;
}

// ---------------- attention weights per batch ----------------
// Per head: QK^T (half-K staged, 32KB LDS), softmax (no max-sub; scores ~O(0.05)),
// accumulate p/z over heads in registers; epilogue: *w_j, row renorm, bf16 out.
__global__ __launch_bounds__(256) void att_kernel(const uint16_t* __restrict__ q,
                                                  const uint16_t* __restrict__ kk_,
                                                  const float* __restrict__ wts,
                                                  const float* __restrict__ padadd,
                                                  uint16_t* __restrict__ aw) {
  __shared__ uint16_t Qs[128 * 64];
  __shared__ uint16_t Ks[128 * 64];
  __shared__ float red[2][128];
  const int b = blockIdx.x;
  const int t = threadIdx.x, l = t & 63, w = t >> 6;
  const int wr = w >> 1, wc = w & 1, l15 = l & 15, hi = l >> 4;
  const int srow = t >> 3;         // 0..31
  const int schunk = (t & 7) * 8;  // 0..56
  const float SCALE = 0.088388347648318447f;  // 1/sqrt(128)

  float wv[4], pv[4];
  #pragma unroll
  for (int n = 0; n < 4; ++n) {
    int j = wc * 64 + n * 16 + l15;
    wv[n] = wts[(size_t)b * 128 + j];
    pv[n] = padadd[(size_t)b * 128 + j];
  }

  f32x4 awacc[4][4];
  #pragma unroll
  for (int m = 0; m < 4; ++m)
    #pragma unroll
    for (int n = 0; n < 4; ++n) awacc[m][n] = (f32x4){0.f, 0.f, 0.f, 0.f};

  for (int h = 0; h < 4; ++h) {
    f32x4 s[4][4];
    #pragma unroll
    for (int m = 0; m < 4; ++m)
      #pragma unroll
      for (int n = 0; n < 4; ++n) s[m][n] = (f32x4){0.f, 0.f, 0.f, 0.f};
    for (int half = 0; half < 2; ++half) {
      #pragma unroll
      for (int i = 0; i < 4; ++i) {
        const int r = i * 32 + srow;
        gld16(&Qs[r * 64 + schunk],
              q + (size_t)(b * 128 + r) * 512 + h * 128 + half * 64 + schunk);
        gld16(&Ks[r * 64 + schunk],
              kk_ + (size_t)(b * 128 + r) * 512 + h * 128 + half * 64 + schunk);
      }
      __syncthreads();
      #pragma unroll
      for (int ks = 0; ks < 2; ++ks) {
        const int k0 = ks * 32 + hi * 8;
        bf16x8 a[4], bb[4];
        #pragma unroll
        for (int m = 0; m < 4; ++m) a[m] = *(const bf16x8*)&Qs[(wr * 64 + m * 16 + l15) * 64 + k0];
        #pragma unroll
        for (int n = 0; n < 4; ++n) bb[n] = *(const bf16x8*)&Ks[(wc * 64 + n * 16 + l15) * 64 + k0];
        #pragma unroll
        for (int m = 0; m < 4; ++m)
          #pragma unroll
          for (int n = 0; n < 4; ++n) s[m][n] = MFMA16(a[m], bb[n], s[m][n]);
      }
      __syncthreads();
    }
    // exp (scores O(0.1): no max-subtraction; -inf pad -> exp = 0)
    #pragma unroll
    for (int m = 0; m < 4; ++m)
      #pragma unroll
      for (int n = 0; n < 4; ++n)
        #pragma unroll
        for (int r = 0; r < 4; ++r)
          s[m][n][r] = __expf(s[m][n][r] * SCALE + pv[n]);
    // per-head row sums -> red[wc][row] (wc halves of the 128 keys)
    #pragma unroll
    for (int m = 0; m < 4; ++m)
      #pragma unroll
      for (int r = 0; r < 4; ++r) {
        float p = s[m][0][r] + s[m][1][r] + s[m][2][r] + s[m][3][r];
        p += __shfl_xor(p, 1); p += __shfl_xor(p, 2);
        p += __shfl_xor(p, 4); p += __shfl_xor(p, 8);
        if (l15 == 0) red[wc][wr * 64 + m * 16 + hi * 4 + r] = p;
      }
    __syncthreads();
    #pragma unroll
    for (int m = 0; m < 4; ++m)
      #pragma unroll
      for (int r = 0; r < 4; ++r) {
        const int row = wr * 64 + m * 16 + hi * 4 + r;
        const float zi = 1.f / (red[0][row] + red[1][row]);
        #pragma unroll
        for (int n = 0; n < 4; ++n) awacc[m][n][r] += s[m][n][r] * zi;
      }
    __syncthreads();
  }
  // multiply by key weights, renormalize each row, write bf16
  #pragma unroll
  for (int m = 0; m < 4; ++m)
    #pragma unroll
    for (int r = 0; r < 4; ++r) {
      float p = awacc[m][0][r] * wv[0] + awacc[m][1][r] * wv[1] +
                awacc[m][2][r] * wv[2] + awacc[m][3][r] * wv[3];
      p += __shfl_xor(p, 1); p += __shfl_xor(p, 2);
      p += __shfl_xor(p, 4); p += __shfl_xor(p, 8);
      if (l15 == 0) red[wc][wr * 64 + m * 16 + hi * 4 + r] = p;
    }
  __syncthreads();
  #pragma unroll
  for (int m = 0; m < 4; ++m)
    #pragma unroll
    for (int r = 0; r < 4; ++r) {
      const int row = wr * 64 + m * 16 + hi * 4 + r;
      const float zi = 1.f / (red[0][row] + red[1][row]);
      #pragma unroll
      for (int n = 0; n < 4; ++n) {
        const int col = wc * 64 + n * 16 + l15;
        aw[(size_t)b * 16384 + (size_t)row * 128 + col] = f2b(awacc[m][n][r] * wv[n] * zi);
      }
    }
}

// ---------------- h = LN(xe + softplus(O)) * g + b, one wave per row of 512 ----------------
__global__ __launch_bounds__(256) void lnh_kernel(const uint16_t* __restrict__ xe,
                                                  const uint16_t* __restrict__ O,
                                                  const float* __restrict__ g,
                                                  const float* __restrict__ be,
                                                  uint16_t* __restrict__ hout) {
  const int t = threadIdx.x, l = t & 63, w = t >> 6;
  const size_t row = (size_t)blockIdx.x * 4 + w;
  const size_t base = row * 512 + l * 8;
  u16x8 xv = *(const u16x8*)(xe + base);
  u16x8 ov = *(const u16x8*)(O + base);
  float hv[8];
  #pragma unroll
  for (int j = 0; j < 8; ++j) {
    float o = b2f(ov[j]);
    float sp = (o > 15.f) ? o : log1pf(__expf(o));
    hv[j] = b2f(xv[j]) + sp;
  }
  float s = 0.f;
  #pragma unroll
  for (int j = 0; j < 8; ++j) s += hv[j];
  #pragma unroll
  for (int m = 1; m < 64; m <<= 1) s += __shfl_xor(s, m);
  const float mu = s * (1.f / 512.f);
  float vs = 0.f;
  #pragma unroll
  for (int j = 0; j < 8; ++j) { float d = hv[j] - mu; vs += d * d; }
  #pragma unroll
  for (int m = 1; m < 64; m <<= 1) vs += __shfl_xor(vs, m);
  const float rstd = rsqrtf(vs * (1.f / 512.f) + 1e-5f);
  u16x8 outv;
  #pragma unroll
  for (int j = 0; j < 8; ++j) {
    const int c = l * 8 + j;
    outv[j] = f2b((hv[j] - mu) * rstd * g[c] + be[c]);
  }
  *(u16x8*)(hout + base) = outv;
}

// =======================================================================================
// Workspace budget (~205 MB peak) with buffer-reuse timeline:
//   B2: x_bf -> k -> O        B1: q -> vin -> h        aw lives in d_out[0:16.8MB]
extern "C" void kernel_launch(void* const* d_in, const int* in_sizes, int n_in,
                              void* d_out, int out_size, void* d_ws, size_t ws_size,
                              hipStream_t stream) {
  (void)in_sizes; (void)n_in; (void)out_size; (void)ws_size;
  const float* x     = (const float*)d_in[0];
  const float* wts   = (const float*)d_in[1];
  const float* emb_W = (const float*)d_in[2];
  const float* emb_b = (const float*)d_in[3];
  const float* wq_W  = (const float*)d_in[4];
  const float* wq_b  = (const float*)d_in[5];
  const float* wk_W  = (const float*)d_in[6];
  const float* wk_b  = (const float*)d_in[7];
  const float* wv_W  = (const float*)d_in[8];
  const float* wv_b  = (const float*)d_in[9];
  const float* ipW   = (const float*)d_in[10];
  const float* ipb   = (const float*)d_in[11];
  const float* ln_g  = (const float*)d_in[12];
  const float* ln_b  = (const float*)d_in[13];
  const float* out_W = (const float*)d_in[14];
  const float* out_b = (const float*)d_in[15];

  char* ws = (char*)d_ws;
  size_t off = 0;
  auto alloc = [&](size_t bytes) { void* p = ws + off; off += (bytes + 255) & ~(size_t)255; return p; };
  uint16_t* emb_bf = (uint16_t*)alloc(131072);
  uint16_t* wqW_bf = (uint16_t*)alloc(524288);
  uint16_t* wkW_bf = (uint16_t*)alloc(524288);
  uint16_t* wvW_bf = (uint16_t*)alloc(524288);
  uint16_t* ip_bf  = (uint16_t*)alloc(1048576);    // in_proj rows 0..1023 (Wq,Wk)
  uint16_t* owW_bf = (uint16_t*)alloc(131072);
  uint16_t* Wqc    = (uint16_t*)alloc(524288);
  uint16_t* Wkc    = (uint16_t*)alloc(524288);
  float*    bqc    = (float*)alloc(2048);
  float*    bkc    = (float*)alloc(2048);
  float*    pad    = (float*)alloc(262144);
  uint16_t* xe     = (uint16_t*)alloc(67108864);   // 65536 x 512 bf16, live to the end
  uint16_t* B1     = (uint16_t*)alloc(67108864);   // q -> vin -> h
  uint16_t* B2     = (uint16_t*)alloc(67108864);   // x_bf -> k -> O

  uint16_t* x_bf = B2;
  uint16_t* qb   = B1;
  uint16_t* kb   = B2;
  uint16_t* aw   = (uint16_t*)d_out;  // first 16.8MB of d_out; consumed before final GEMM
  uint16_t* vin  = B1;
  uint16_t* Ob   = B2;
  uint16_t* hb   = B1;

  const int TB = 256;
  // packs
  pack_bf16<<<8192, TB, 0, stream>>>(x, x_bf, 2097152);
  pack_bf16<<<64,   TB, 0, stream>>>(emb_W, emb_bf, 16384);
  pack_bf16<<<256,  TB, 0, stream>>>(wq_W, wqW_bf, 65536);
  pack_bf16<<<256,  TB, 0, stream>>>(wk_W, wkW_bf, 65536);
  pack_bf16<<<256,  TB, 0, stream>>>(wv_W, wvW_bf, 65536);
  pack_bf16<<<512,  TB, 0, stream>>>(ipW, ip_bf, 131072);
  pack_bf16<<<64,   TB, 0, stream>>>(out_W, owW_bf, 16384);
  // combined projection biases (f32): bqc = Wq@wq_b + bq ; bkc = Wk@wk_b + bk
  combine_bias<<<128, TB, 0, stream>>>(ipW, wq_b, ipb, bqc);
  combine_bias<<<128, TB, 0, stream>>>(ipW + 262144, wk_b, ipb + 512, bkc);
  // combined projection weights: Wqc = Wq @ wq_W ; Wkc = Wk @ wk_W   (512x512x512)
  gemm_ab_kernel<<<dim3(4, 4, 1), TB, 0, stream>>>(ip_bf, 512, 0, wqW_bf, 512, 0, Wqc, 512, 0, 512);
  gemm_ab_kernel<<<dim3(4, 4, 1), TB, 0, stream>>>(ip_bf + 262144, 512, 0, wkW_bf, 512, 0, Wkc, 512, 0, 512);
  // xe = x @ emb_W^T + emb_b   (65536 x 512, K=128)
  gemm_bt_kernel<uint16_t><<<dim3(4, 512), TB, 0, stream>>>(x_bf, emb_bf, emb_b, xe, 512, 128);
  pad_kernel<<<16384, TB, 0, stream>>>(xe, pad);
  // q = xe @ Wqc^T + bqc -> B1 ; k = xe @ Wkc^T + bkc -> B2 (x_bf dead)
  gemm_bt_kernel<uint16_t><<<dim3(4, 512), TB, 0, stream>>>(xe, Wqc, bqc, qb, 512, 512);
  gemm_bt_kernel<uint16_t><<<dim3(4, 512), TB, 0, stream>>>(xe, Wkc, bkc, kb, 512, 512);
  // attention weights -> aw (in d_out)
  att_kernel<<<512, TB, 0, stream>>>(qb, kb, wts, pad, aw);
  // v_in = xe @ wv^T + wv_b -> B1 (q dead)
  gemm_bt_kernel<uint16_t><<<dim3(4, 512), TB, 0, stream>>>(xe, wvW_bf, wv_b, vin, 512, 512);
  // att_output = aw @ v_in -> B2 (k dead)   (batched 128x512x128)
  gemm_ab_kernel<<<dim3(4, 1, 512), TB, 0, stream>>>(aw, 128, 16384, vin, 512, 65536,
                                                     Ob, 512, 65536, 128);
  // h = LN(xe + softplus(O)) -> B1 (vin dead)
  lnh_kernel<<<16384, TB, 0, stream>>>(xe, Ob, ln_g, ln_b, hb);
  // out = h @ out_W^T + out_b   (65536 x 128, K=512), f32 (overwrites aw region last)
  gemm_bt_kernel<float><<<dim3(1, 512), TB, 0, stream>>>(hb, owW_bf, out_b, (float*)d_out, 128, 512);
}

// Round 4
// 478.746 us; speedup vs baseline: 1.1459x; 1.1459x over previous
//
#include <hip/hip_runtime.h>
#include <stdint.h>

// Shapes (fixed): B=512, N=128, E=128, H=4, D=512, hd=128.

typedef __attribute__((ext_vector_type(8))) __bf16 bf16x8;
typedef __attribute__((ext_vector_type(8))) uint16_t u16x8;
typedef __attribute__((ext_vector_type(4))) float f32x4;

__device__ __forceinline__ float b2f(uint16_t h) {
  union { uint32_t u; float f; } c; c.u = ((uint32_t)h) << 16; return c.f;
}
__device__ __forceinline__ uint16_t f2b(float f) {
  union { float f; uint32_t u; } c; c.f = f;
  return (uint16_t)((c.u + 0x7fffu + ((c.u >> 16) & 1u)) >> 16);
}
__device__ __forceinline__ void gld16(void* lds, const void* g) {
  __builtin_amdgcn_global_load_lds(
      (const __attribute__((address_space(1))) uint32_t*)(g),
      (__attribute__((address_space(3))) uint32_t*)(lds),
      16, 0, 0);
}
__device__ __forceinline__ void stc(float* C, size_t i, float v) { C[i] = v; }
__device__ __forceinline__ void stc(uint16_t* C, size_t i, float v) { C[i] = f2b(v); }

#define MFMA16(a, b, c) __builtin_amdgcn_mfma_f32_16x16x32_bf16((a), (b), (c), 0, 0, 0)

// ---------------- pack f32 -> bf16 (4 elems/thread) ----------------
__global__ __launch_bounds__(256) void pack_bf16(const float* __restrict__ in,
                                                 uint16_t* __restrict__ out, int n4) {
  int i = blockIdx.x * 256 + threadIdx.x;
  if (i >= n4) return;
  float4 v = ((const float4*)in)[i];
  ushort4 o;
  o.x = f2b(v.x); o.y = f2b(v.y); o.z = f2b(v.z); o.w = f2b(v.w);
  ((ushort4*)out)[i] = o;
}

// ---------------- bqc[i] = b2[i] + sum_k Wbig[i,k]*b1[k]  (512x512, f32) ----------------
__global__ __launch_bounds__(256) void combine_bias(const float* __restrict__ Wbig,
                                                    const float* __restrict__ b1,
                                                    const float* __restrict__ b2,
                                                    float* __restrict__ out) {
  const int t = threadIdx.x, l = t & 63, w = t >> 6;
  const int row = blockIdx.x * 4 + w;
  float s = 0.f;
  #pragma unroll
  for (int j = 0; j < 8; ++j) {
    int c = j * 64 + l;
    s += Wbig[(size_t)row * 512 + c] * b1[c];
  }
  #pragma unroll
  for (int m = 1; m < 64; m <<= 1) s += __shfl_xor(s, m);
  if (l == 0) out[row] = s + b2[row];
}

// ---------------- C(MxN) = A(MxK) @ W(NxK)^T + bias ; 128x128 tile, BK=64 ----------------
template <typename OT>
__global__ __launch_bounds__(256) void gemm_bt_kernel(
    const uint16_t* __restrict__ A, const uint16_t* __restrict__ W,
    const float* __restrict__ bias, OT* __restrict__ C, int N, int K) {
  __shared__ uint16_t As[128 * 64];
  __shared__ uint16_t Bs[128 * 64];
  const int t = threadIdx.x, l = t & 63, w = t >> 6;
  const int wr = w >> 1, wc = w & 1, l15 = l & 15, hi = l >> 4;
  const int mtile = blockIdx.y, ntile = blockIdx.x;
  f32x4 acc[4][4];
  #pragma unroll
  for (int m = 0; m < 4; ++m)
    #pragma unroll
    for (int n = 0; n < 4; ++n) acc[m][n] = (f32x4){0.f, 0.f, 0.f, 0.f};
  const int srow = t >> 3, schunk = (t & 7) * 8;
  const int nk = K >> 6;
  const int rowA0 = mtile * 128, rowB0 = ntile * 128;
  for (int kt = 0; kt < nk; ++kt) {
    const int kb = kt << 6;
    #pragma unroll
    for (int i = 0; i < 4; ++i) {
      const int r = i * 32 + srow;
      gld16(&As[r * 64 + schunk], A + (size_t)(rowA0 + r) * K + kb + schunk);
      gld16(&Bs[r * 64 + schunk], W + (size_t)(rowB0 + r) * K + kb + schunk);
    }
    __syncthreads();
    #pragma unroll
    for (int ks = 0; ks < 2; ++ks) {
      const int k0 = ks * 32 + hi * 8;
      bf16x8 a[4], bb[4];
      #pragma unroll
      for (int m = 0; m < 4; ++m) a[m] = *(const bf16x8*)&As[(wr * 64 + m * 16 + l15) * 64 + k0];
      #pragma unroll
      for (int n = 0; n < 4; ++n) bb[n] = *(const bf16x8*)&Bs[(wc * 64 + n * 16 + l15) * 64 + k0];
      #pragma unroll
      for (int m = 0; m < 4; ++m)
        #pragma unroll
        for (int n = 0; n < 4; ++n) acc[m][n] = MFMA16(a[m], bb[n], acc[m][n]);
    }
    __syncthreads();
  }
  #pragma unroll
  for (int m = 0; m < 4; ++m) {
    const int row = rowA0 + wr * 64 + m * 16 + hi * 4;
    #pragma unroll
    for (int n = 0; n < 4; ++n) {
      const int col = rowB0 + wc * 64 + n * 16 + l15;
      const float bv = bias[col];
      #pragma unroll
      for (int r = 0; r < 4; ++r)
        stc(C, (size_t)(row + r) * N + col, acc[m][n][r] + bv);
    }
  }
}

// ---------------- C = A(MxK) @ B(KxN), B row-major (transpose-staged), bf16 out, batched ----
__global__ __launch_bounds__(256) void gemm_ab_kernel(
    const uint16_t* __restrict__ A, int lda, long long sA,
    const uint16_t* __restrict__ B, int ldb, long long sB,
    uint16_t* __restrict__ C, int ldc, long long sC, int K) {
  __shared__ uint16_t As[128 * 64];
  __shared__ uint16_t Bt[128 * 64];  // [n][k]
  const int t = threadIdx.x, l = t & 63, w = t >> 6;
  const int wr = w >> 1, wc = w & 1, l15 = l & 15, hi = l >> 4;
  const int mtile = blockIdx.y, ntile = blockIdx.x, bz = blockIdx.z;
  const uint16_t* Ab = A + (size_t)bz * sA;
  const uint16_t* Bb = B + (size_t)bz * sB;
  uint16_t* Cb = C + (size_t)bz * sC;
  f32x4 acc[4][4];
  #pragma unroll
  for (int m = 0; m < 4; ++m)
    #pragma unroll
    for (int n = 0; n < 4; ++n) acc[m][n] = (f32x4){0.f, 0.f, 0.f, 0.f};
  const int srow = t >> 3, schunk = (t & 7) * 8;
  const int nk = K >> 6;
  for (int kt = 0; kt < nk; ++kt) {
    const int kb = kt << 6;
    #pragma unroll
    for (int i = 0; i < 4; ++i) {
      const int r = i * 32 + srow;
      gld16(&As[r * 64 + schunk], Ab + (size_t)(mtile * 128 + r) * lda + kb + schunk);
    }
    #pragma unroll
    for (int rd = 0; rd < 4; ++rd) {
      const int id = rd * 256 + t;
      const int kr = id >> 4;
      const int c = (id & 15) * 8;
      u16x8 gv = *(const u16x8*)(Bb + (size_t)(kb + kr) * ldb + ntile * 128 + c);
      #pragma unroll
      for (int j = 0; j < 8; ++j) Bt[(c + j) * 64 + kr] = gv[j];
    }
    __syncthreads();
    #pragma unroll
    for (int ks = 0; ks < 2; ++ks) {
      const int k0 = ks * 32 + hi * 8;
      bf16x8 a[4], bb[4];
      #pragma unroll
      for (int m = 0; m < 4; ++m) a[m] = *(const bf16x8*)&As[(wr * 64 + m * 16 + l15) * 64 + k0];
      #pragma unroll
      for (int n = 0; n < 4; ++n) bb[n] = *(const bf16x8*)&Bt[(wc * 64 + n * 16 + l15) * 64 + k0];
      #pragma unroll
      for (int m = 0; m < 4; ++m)
        #pragma unroll
        for (int n = 0; n < 4; ++n) acc[m][n] = MFMA16(a[m], bb[n], acc[m][n]);
    }
    __syncthreads();
  }
  #pragma unroll
  for (int m = 0; m < 4; ++m) {
    const int row = mtile * 128 + wr * 64 + m * 16 + hi * 4;
    #pragma unroll
    for (int n = 0; n < 4; ++n) {
      const int col = ntile * 128 + wc * 64 + n * 16 + l15;
      #pragma unroll
      for (int r = 0; r < 4; ++r)
        Cb[(size_t)(row + r) * ldc + col] = f2b(acc[m][n][r]);
    }
  }
}

// ---------------- pad flags: -inf where row of xe is all-zero ----------------
__global__ __launch_bounds__(256) void pad_kernel(const uint16_t* __restrict__ xe,
                                                  float* __restrict__ padadd) {
  const int t = threadIdx.x, l = t & 63, w = t >> 6;
  const size_t row = (size_t)blockIdx.x * 4 + w;
  u16x8 v = *(const u16x8*)(xe + row * 512 + l * 8);
  float s = 0.f;
  #pragma unroll
  for (int j = 0; j < 8; ++j) s += fabsf(b2f(v[j]));
  #pragma unroll
  for (int m = 1; m < 64; m <<= 1) s += __shfl_xor(s, m);
  if (l == 0) padadd[row] = (s == 0.f) ? -__builtin_inff() : 0.f;
}

// ---------------- attention weights per batch ----------------
// Per head: QK^T (half-K staged, 32KB LDS), softmax (no max-sub; scores ~O(0.05)),
// accumulate p/z over heads in registers; epilogue: *w_j, row renorm, bf16 out.
__global__ __launch_bounds__(256) void att_kernel(const uint16_t* __restrict__ q,
                                                  const uint16_t* __restrict__ kk_,
                                                  const float* __restrict__ wts,
                                                  const float* __restrict__ padadd,
                                                  uint16_t* __restrict__ aw) {
  __shared__ uint16_t Qs[128 * 64];
  __shared__ uint16_t Ks[128 * 64];
  __shared__ float red[2][128];
  const int b = blockIdx.x;
  const int t = threadIdx.x, l = t & 63, w = t >> 6;
  const int wr = w >> 1, wc = w & 1, l15 = l & 15, hi = l >> 4;
  const int srow = t >> 3;         // 0..31
  const int schunk = (t & 7) * 8;  // 0..56
  const float SCALE = 0.088388347648318447f;  // 1/sqrt(128)

  float wv[4], pv[4];
  #pragma unroll
  for (int n = 0; n < 4; ++n) {
    int j = wc * 64 + n * 16 + l15;
    wv[n] = wts[(size_t)b * 128 + j];
    pv[n] = padadd[(size_t)b * 128 + j];
  }

  f32x4 awacc[4][4];
  #pragma unroll
  for (int m = 0; m < 4; ++m)
    #pragma unroll
    for (int n = 0; n < 4; ++n) awacc[m][n] = (f32x4){0.f, 0.f, 0.f, 0.f};

  for (int h = 0; h < 4; ++h) {
    f32x4 s[4][4];
    #pragma unroll
    for (int m = 0; m < 4; ++m)
      #pragma unroll
      for (int n = 0; n < 4; ++n) s[m][n] = (f32x4){0.f, 0.f, 0.f, 0.f};
    for (int half = 0; half < 2; ++half) {
      #pragma unroll
      for (int i = 0; i < 4; ++i) {
        const int r = i * 32 + srow;
        gld16(&Qs[r * 64 + schunk],
              q + (size_t)(b * 128 + r) * 512 + h * 128 + half * 64 + schunk);
        gld16(&Ks[r * 64 + schunk],
              kk_ + (size_t)(b * 128 + r) * 512 + h * 128 + half * 64 + schunk);
      }
      __syncthreads();
      #pragma unroll
      for (int ks = 0; ks < 2; ++ks) {
        const int k0 = ks * 32 + hi * 8;
        bf16x8 a[4], bb[4];
        #pragma unroll
        for (int m = 0; m < 4; ++m) a[m] = *(const bf16x8*)&Qs[(wr * 64 + m * 16 + l15) * 64 + k0];
        #pragma unroll
        for (int n = 0; n < 4; ++n) bb[n] = *(const bf16x8*)&Ks[(wc * 64 + n * 16 + l15) * 64 + k0];
        #pragma unroll
        for (int m = 0; m < 4; ++m)
          #pragma unroll
          for (int n = 0; n < 4; ++n) s[m][n] = MFMA16(a[m], bb[n], s[m][n]);
      }
      __syncthreads();
    }
    // exp (scores O(0.1): no max-subtraction; -inf pad -> exp = 0)
    #pragma unroll
    for (int m = 0; m < 4; ++m)
      #pragma unroll
      for (int n = 0; n < 4; ++n)
        #pragma unroll
        for (int r = 0; r < 4; ++r)
          s[m][n][r] = __expf(s[m][n][r] * SCALE + pv[n]);
    // per-head row sums -> red[wc][row] (wc halves of the 128 keys)
    #pragma unroll
    for (int m = 0; m < 4; ++m)
      #pragma unroll
      for (int r = 0; r < 4; ++r) {
        float p = s[m][0][r] + s[m][1][r] + s[m][2][r] + s[m][3][r];
        p += __shfl_xor(p, 1); p += __shfl_xor(p, 2);
        p += __shfl_xor(p, 4); p += __shfl_xor(p, 8);
        if (l15 == 0) red[wc][wr * 64 + m * 16 + hi * 4 + r] = p;
      }
    __syncthreads();
    #pragma unroll
    for (int m = 0; m < 4; ++m)
      #pragma unroll
      for (int r = 0; r < 4; ++r) {
        const int row = wr * 64 + m * 16 + hi * 4 + r;
        const float zi = 1.f / (red[0][row] + red[1][row]);
        #pragma unroll
        for (int n = 0; n < 4; ++n) awacc[m][n][r] += s[m][n][r] * zi;
      }
    __syncthreads();
  }
  // multiply by key weights, renormalize each row, write bf16
  #pragma unroll
  for (int m = 0; m < 4; ++m)
    #pragma unroll
    for (int r = 0; r < 4; ++r) {
      float p = awacc[m][0][r] * wv[0] + awacc[m][1][r] * wv[1] +
                awacc[m][2][r] * wv[2] + awacc[m][3][r] * wv[3];
      p += __shfl_xor(p, 1); p += __shfl_xor(p, 2);
      p += __shfl_xor(p, 4); p += __shfl_xor(p, 8);
      if (l15 == 0) red[wc][wr * 64 + m * 16 + hi * 4 + r] = p;
    }
  __syncthreads();
  #pragma unroll
  for (int m = 0; m < 4; ++m)
    #pragma unroll
    for (int r = 0; r < 4; ++r) {
      const int row = wr * 64 + m * 16 + hi * 4 + r;
      const float zi = 1.f / (red[0][row] + red[1][row]);
      #pragma unroll
      for (int n = 0; n < 4; ++n) {
        const int col = wc * 64 + n * 16 + l15;
        aw[(size_t)b * 16384 + (size_t)row * 128 + col] = f2b(awacc[m][n][r] * wv[n] * zi);
      }
    }
}

// ---------------- h = LN(xe + softplus(O)) * g + b, one wave per row of 512 ----------------
// softplus via fast HW transcendentals: max(o,0) + log(1 + exp(-|o|)); arg of log in (1,2].
__global__ __launch_bounds__(256) void lnh_kernel(const uint16_t* __restrict__ xe,
                                                  const uint16_t* __restrict__ O,
                                                  const float* __restrict__ g,
                                                  const float* __restrict__ be,
                                                  uint16_t* __restrict__ hout) {
  const int t = threadIdx.x, l = t & 63, w = t >> 6;
  const size_t row = (size_t)blockIdx.x * 4 + w;
  const size_t base = row * 512 + l * 8;
  u16x8 xv = *(const u16x8*)(xe + base);
  u16x8 ov = *(const u16x8*)(O + base);
  float hv[8];
  #pragma unroll
  for (int j = 0; j < 8; ++j) {
    float o = b2f(ov[j]);
    float sp = fmaxf(o, 0.f) + __logf(1.f + __expf(-fabsf(o)));
    hv[j] = b2f(xv[j]) + sp;
  }
  float s = 0.f;
  #pragma unroll
  for (int j = 0; j < 8; ++j) s += hv[j];
  #pragma unroll
  for (int m = 1; m < 64; m <<= 1) s += __shfl_xor(s, m);
  const float mu = s * (1.f / 512.f);
  float vs = 0.f;
  #pragma unroll
  for (int j = 0; j < 8; ++j) { float d = hv[j] - mu; vs += d * d; }
  #pragma unroll
  for (int m = 1; m < 64; m <<= 1) vs += __shfl_xor(vs, m);
  const float rstd = rsqrtf(vs * (1.f / 512.f) + 1e-5f);
  u16x8 outv;
  #pragma unroll
  for (int j = 0; j < 8; ++j) {
    const int c = l * 8 + j;
    outv[j] = f2b((hv[j] - mu) * rstd * g[c] + be[c]);
  }
  *(u16x8*)(hout + base) = outv;
}

// =======================================================================================
// Workspace budget (~205 MB peak) with buffer-reuse timeline:
//   B2: x_bf -> k -> O        B1: q -> vin -> h        aw lives in d_out[0:16.8MB]
extern "C" void kernel_launch(void* const* d_in, const int* in_sizes, int n_in,
                              void* d_out, int out_size, void* d_ws, size_t ws_size,
                              hipStream_t stream) {
  (void)in_sizes; (void)n_in; (void)out_size; (void)ws_size;
  const float* x     = (const float*)d_in[0];
  const float* wts   = (const float*)d_in[1];
  const float* emb_W = (const float*)d_in[2];
  const float* emb_b = (const float*)d_in[3];
  const float* wq_W  = (const float*)d_in[4];
  const float* wq_b  = (const float*)d_in[5];
  const float* wk_W  = (const float*)d_in[6];
  const float* wk_b  = (const float*)d_in[7];
  const float* wv_W  = (const float*)d_in[8];
  const float* wv_b  = (const float*)d_in[9];
  const float* ipW   = (const float*)d_in[10];
  const float* ipb   = (const float*)d_in[11];
  const float* ln_g  = (const float*)d_in[12];
  const float* ln_b  = (const float*)d_in[13];
  const float* out_W = (const float*)d_in[14];
  const float* out_b = (const float*)d_in[15];

  char* ws = (char*)d_ws;
  size_t off = 0;
  auto alloc = [&](size_t bytes) { void* p = ws + off; off += (bytes + 255) & ~(size_t)255; return p; };
  uint16_t* emb_bf = (uint16_t*)alloc(131072);
  uint16_t* wqW_bf = (uint16_t*)alloc(524288);
  uint16_t* wkW_bf = (uint16_t*)alloc(524288);
  uint16_t* wvW_bf = (uint16_t*)alloc(524288);
  uint16_t* ip_bf  = (uint16_t*)alloc(1048576);    // in_proj rows 0..1023 (Wq,Wk)
  uint16_t* owW_bf = (uint16_t*)alloc(131072);
  uint16_t* Wqc    = (uint16_t*)alloc(524288);
  uint16_t* Wkc    = (uint16_t*)alloc(524288);
  float*    bqc    = (float*)alloc(2048);
  float*    bkc    = (float*)alloc(2048);
  float*    pad    = (float*)alloc(262144);
  uint16_t* xe     = (uint16_t*)alloc(67108864);   // 65536 x 512 bf16, live to the end
  uint16_t* B1     = (uint16_t*)alloc(67108864);   // q -> vin -> h
  uint16_t* B2     = (uint16_t*)alloc(67108864);   // x_bf -> k -> O

  uint16_t* x_bf = B2;
  uint16_t* qb   = B1;
  uint16_t* kb   = B2;
  uint16_t* aw   = (uint16_t*)d_out;  // first 16.8MB of d_out; consumed before final GEMM
  uint16_t* vin  = B1;
  uint16_t* Ob   = B2;
  uint16_t* hb   = B1;

  const int TB = 256;
  // packs
  pack_bf16<<<8192, TB, 0, stream>>>(x, x_bf, 2097152);
  pack_bf16<<<64,   TB, 0, stream>>>(emb_W, emb_bf, 16384);
  pack_bf16<<<256,  TB, 0, stream>>>(wq_W, wqW_bf, 65536);
  pack_bf16<<<256,  TB, 0, stream>>>(wk_W, wkW_bf, 65536);
  pack_bf16<<<256,  TB, 0, stream>>>(wv_W, wvW_bf, 65536);
  pack_bf16<<<512,  TB, 0, stream>>>(ipW, ip_bf, 131072);
  pack_bf16<<<64,   TB, 0, stream>>>(out_W, owW_bf, 16384);
  // combined projection biases (f32): bqc = Wq@wq_b + bq ; bkc = Wk@wk_b + bk
  combine_bias<<<128, TB, 0, stream>>>(ipW, wq_b, ipb, bqc);
  combine_bias<<<128, TB, 0, stream>>>(ipW + 262144, wk_b, ipb + 512, bkc);
  // combined projection weights: Wqc = Wq @ wq_W ; Wkc = Wk @ wk_W   (512x512x512)
  gemm_ab_kernel<<<dim3(4, 4, 1), TB, 0, stream>>>(ip_bf, 512, 0, wqW_bf, 512, 0, Wqc, 512, 0, 512);
  gemm_ab_kernel<<<dim3(4, 4, 1), TB, 0, stream>>>(ip_bf + 262144, 512, 0, wkW_bf, 512, 0, Wkc, 512, 0, 512);
  // xe = x @ emb_W^T + emb_b   (65536 x 512, K=128)
  gemm_bt_kernel<uint16_t><<<dim3(4, 512), TB, 0, stream>>>(x_bf, emb_bf, emb_b, xe, 512, 128);
  pad_kernel<<<16384, TB, 0, stream>>>(xe, pad);
  // q = xe @ Wqc^T + bqc -> B1 ; k = xe @ Wkc^T + bkc -> B2 (x_bf dead)
  gemm_bt_kernel<uint16_t><<<dim3(4, 512), TB, 0, stream>>>(xe, Wqc, bqc, qb, 512, 512);
  gemm_bt_kernel<uint16_t><<<dim3(4, 512), TB, 0, stream>>>(xe, Wkc, bkc, kb, 512, 512);
  // attention weights -> aw (in d_out)
  att_kernel<<<512, TB, 0, stream>>>(qb, kb, wts, pad, aw);
  // v_in = xe @ wv^T + wv_b -> B1 (q dead)
  gemm_bt_kernel<uint16_t><<<dim3(4, 512), TB, 0, stream>>>(xe, wvW_bf, wv_b, vin, 512, 512);
  // att_output = aw @ v_in -> B2 (k dead)   (batched 128x512x128)
  gemm_ab_kernel<<<dim3(4, 1, 512), TB, 0, stream>>>(aw, 128, 16384, vin, 512, 65536,
                                                     Ob, 512, 65536, 128);
  // h = LN(xe + softplus(O)) -> B1 (vin dead)
  lnh_kernel<<<16384, TB, 0, stream>>>(xe, Ob, ln_g, ln_b, hb);
  // out = h @ out_W^T + out_b   (65536 x 128, K=512), f32 (overwrites aw region last)
  gemm_bt_kernel<float><<<dim3(1, 512), TB, 0, stream>>>(hb, owW_bf, out_b, (float*)d_out, 128, 512);
}

// Round 5
// 439.760 us; speedup vs baseline: 1.2475x; 1.0887x over previous
//
#include <hip/hip_runtime.h>
#include <stdint.h>

// Shapes (fixed): B=512, N=128, E=128, H=4, D=512, hd=128.

typedef __attribute__((ext_vector_type(8))) __bf16 bf16x8;
typedef __attribute__((ext_vector_type(8))) uint16_t u16x8;
typedef __attribute__((ext_vector_type(4))) float f32x4;

__device__ __forceinline__ float b2f(uint16_t h) {
  union { uint32_t u; float f; } c; c.u = ((uint32_t)h) << 16; return c.f;
}
__device__ __forceinline__ uint16_t f2b(float f) {
  union { float f; uint32_t u; } c; c.f = f;
  return (uint16_t)((c.u + 0x7fffu + ((c.u >> 16) & 1u)) >> 16);
}
__device__ __forceinline__ void gld16(void* lds, const void* g) {
  __builtin_amdgcn_global_load_lds(
      (const __attribute__((address_space(1))) uint32_t*)(g),
      (__attribute__((address_space(3))) uint32_t*)(lds),
      16, 0, 0);
}
__device__ __forceinline__ void stc(float* C, size_t i, float v) { C[i] = v; }
__device__ __forceinline__ void stc(uint16_t* C, size_t i, float v) { C[i] = f2b(v); }

#define MFMA16(a, b, c) __builtin_amdgcn_mfma_f32_16x16x32_bf16((a), (b), (c), 0, 0, 0)

// ---------------- pack f32 -> bf16 (4 elems/thread) ----------------
__global__ __launch_bounds__(256) void pack_bf16(const float* __restrict__ in,
                                                 uint16_t* __restrict__ out, int n4) {
  int i = blockIdx.x * 256 + threadIdx.x;
  if (i >= n4) return;
  float4 v = ((const float4*)in)[i];
  ushort4 o;
  o.x = f2b(v.x); o.y = f2b(v.y); o.z = f2b(v.z); o.w = f2b(v.w);
  ((ushort4*)out)[i] = o;
}

// ---------------- bqc[i] = b2[i] + sum_k Wbig[i,k]*b1[k]  (512x512, f32) ----------------
__global__ __launch_bounds__(256) void combine_bias(const float* __restrict__ Wbig,
                                                    const float* __restrict__ b1,
                                                    const float* __restrict__ b2,
                                                    float* __restrict__ out) {
  const int t = threadIdx.x, l = t & 63, w = t >> 6;
  const int row = blockIdx.x * 4 + w;
  float s = 0.f;
  #pragma unroll
  for (int j = 0; j < 8; ++j) {
    int c = j * 64 + l;
    s += Wbig[(size_t)row * 512 + c] * b1[c];
  }
  #pragma unroll
  for (int m = 1; m < 64; m <<= 1) s += __shfl_xor(s, m);
  if (l == 0) out[row] = s + b2[row];
}

// ---------------- C(MxN) = A(MxK) @ W(NxK)^T + bias ; 128x128 tile, BK=64 ----------------
// Double-buffered LDS, counted vmcnt(8) across raw s_barrier (loads stay in flight),
// XCD-chunked block swizzle (same-A blocks share one XCD L2).
template <typename OT>
__global__ __launch_bounds__(256) void gemm_bt_kernel(
    const uint16_t* __restrict__ A, const uint16_t* __restrict__ W,
    const float* __restrict__ bias, OT* __restrict__ C, int N, int K) {
  __shared__ uint16_t As[2][128 * 64];
  __shared__ uint16_t Bs[2][128 * 64];
  const int t = threadIdx.x, l = t & 63, w = t >> 6;
  const int wr = w >> 1, wc = w & 1, l15 = l & 15, hi = l >> 4;
  // bijective XCD-chunk swizzle (nwg is a multiple of 8 for all our grids)
  const int gx = gridDim.x;
  const int nwg = gx * gridDim.y;
  const int lin = blockIdx.x + gx * blockIdx.y;
  const int cpx = nwg >> 3;
  const int sw = (lin & 7) * cpx + (lin >> 3);
  const int ntile = sw % gx, mtile = sw / gx;
  f32x4 acc[4][4];
  #pragma unroll
  for (int m = 0; m < 4; ++m)
    #pragma unroll
    for (int n = 0; n < 4; ++n) acc[m][n] = (f32x4){0.f, 0.f, 0.f, 0.f};
  const int srow = t >> 3, schunk = (t & 7) * 8;
  const int nk = K >> 6;
  const int rowA0 = mtile * 128, rowB0 = ntile * 128;
  auto stage = [&](int kt, int buf) {
    const int kb = kt << 6;
    #pragma unroll
    for (int i = 0; i < 4; ++i) {
      const int r = i * 32 + srow;
      gld16(&As[buf][r * 64 + schunk], A + (size_t)(rowA0 + r) * K + kb + schunk);
      gld16(&Bs[buf][r * 64 + schunk], W + (size_t)(rowB0 + r) * K + kb + schunk);
    }
  };
  stage(0, 0);
  for (int kt = 0; kt < nk; ++kt) {
    const int cur = kt & 1;
    if (kt + 1 < nk) {
      stage(kt + 1, cur ^ 1);                      // 8 loads in flight for next tile
      asm volatile("s_waitcnt vmcnt(8)" ::: "memory");  // current tile's 8 done
    } else {
      asm volatile("s_waitcnt vmcnt(0)" ::: "memory");
    }
    __builtin_amdgcn_s_barrier();
    asm volatile("" ::: "memory");                 // keep ds_reads below the barrier
    #pragma unroll
    for (int ks = 0; ks < 2; ++ks) {
      const int k0 = ks * 32 + hi * 8;
      bf16x8 a[4], bb[4];
      #pragma unroll
      for (int m = 0; m < 4; ++m)
        a[m] = *(const bf16x8*)&As[cur][(wr * 64 + m * 16 + l15) * 64 + k0];
      #pragma unroll
      for (int n = 0; n < 4; ++n)
        bb[n] = *(const bf16x8*)&Bs[cur][(wc * 64 + n * 16 + l15) * 64 + k0];
      #pragma unroll
      for (int m = 0; m < 4; ++m)
        #pragma unroll
        for (int n = 0; n < 4; ++n) acc[m][n] = MFMA16(a[m], bb[n], acc[m][n]);
    }
    asm volatile("" ::: "memory");
    __builtin_amdgcn_s_barrier();                  // buf[cur] free for overwrite at kt+2
  }
  #pragma unroll
  for (int m = 0; m < 4; ++m) {
    const int row = rowA0 + wr * 64 + m * 16 + hi * 4;
    #pragma unroll
    for (int n = 0; n < 4; ++n) {
      const int col = rowB0 + wc * 64 + n * 16 + l15;
      const float bv = bias[col];
      #pragma unroll
      for (int r = 0; r < 4; ++r)
        stc(C, (size_t)(row + r) * N + col, acc[m][n][r] + bv);
    }
  }
}

// ---------------- C = A(MxK) @ B(KxN), B row-major (transpose-staged), bf16 out, batched ----
__global__ __launch_bounds__(256) void gemm_ab_kernel(
    const uint16_t* __restrict__ A, int lda, long long sA,
    const uint16_t* __restrict__ B, int ldb, long long sB,
    uint16_t* __restrict__ C, int ldc, long long sC, int K) {
  __shared__ uint16_t As[128 * 64];
  __shared__ uint16_t Bt[128 * 64];  // [n][k]
  const int t = threadIdx.x, l = t & 63, w = t >> 6;
  const int wr = w >> 1, wc = w & 1, l15 = l & 15, hi = l >> 4;
  // XCD-chunk swizzle over the full 3D grid
  const int gx = gridDim.x, gy = gridDim.y;
  const int nwg = gx * gy * gridDim.z;
  const int lin = blockIdx.x + gx * (blockIdx.y + gy * blockIdx.z);
  const int cpx = nwg >> 3;
  const int sw = (lin & 7) * cpx + (lin >> 3);
  const int ntile = sw % gx;
  const int rest = sw / gx;
  const int mtile = rest % gy, bz = rest / gy;
  const uint16_t* Ab = A + (size_t)bz * sA;
  const uint16_t* Bb = B + (size_t)bz * sB;
  uint16_t* Cb = C + (size_t)bz * sC;
  f32x4 acc[4][4];
  #pragma unroll
  for (int m = 0; m < 4; ++m)
    #pragma unroll
    for (int n = 0; n < 4; ++n) acc[m][n] = (f32x4){0.f, 0.f, 0.f, 0.f};
  const int srow = t >> 3, schunk = (t & 7) * 8;
  const int nk = K >> 6;
  for (int kt = 0; kt < nk; ++kt) {
    const int kb = kt << 6;
    #pragma unroll
    for (int i = 0; i < 4; ++i) {
      const int r = i * 32 + srow;
      gld16(&As[r * 64 + schunk], Ab + (size_t)(mtile * 128 + r) * lda + kb + schunk);
    }
    #pragma unroll
    for (int rd = 0; rd < 4; ++rd) {
      const int id = rd * 256 + t;
      const int kr = id >> 4;
      const int c = (id & 15) * 8;
      u16x8 gv = *(const u16x8*)(Bb + (size_t)(kb + kr) * ldb + ntile * 128 + c);
      #pragma unroll
      for (int j = 0; j < 8; ++j) Bt[(c + j) * 64 + kr] = gv[j];
    }
    __syncthreads();
    #pragma unroll
    for (int ks = 0; ks < 2; ++ks) {
      const int k0 = ks * 32 + hi * 8;
      bf16x8 a[4], bb[4];
      #pragma unroll
      for (int m = 0; m < 4; ++m) a[m] = *(const bf16x8*)&As[(wr * 64 + m * 16 + l15) * 64 + k0];
      #pragma unroll
      for (int n = 0; n < 4; ++n) bb[n] = *(const bf16x8*)&Bt[(wc * 64 + n * 16 + l15) * 64 + k0];
      #pragma unroll
      for (int m = 0; m < 4; ++m)
        #pragma unroll
        for (int n = 0; n < 4; ++n) acc[m][n] = MFMA16(a[m], bb[n], acc[m][n]);
    }
    __syncthreads();
  }
  #pragma unroll
  for (int m = 0; m < 4; ++m) {
    const int row = mtile * 128 + wr * 64 + m * 16 + hi * 4;
    #pragma unroll
    for (int n = 0; n < 4; ++n) {
      const int col = ntile * 128 + wc * 64 + n * 16 + l15;
      #pragma unroll
      for (int r = 0; r < 4; ++r)
        Cb[(size_t)(row + r) * ldc + col] = f2b(acc[m][n][r]);
    }
  }
}

// ---------------- pad flags: -inf where row of xe is all-zero ----------------
__global__ __launch_bounds__(256) void pad_kernel(const uint16_t* __restrict__ xe,
                                                  float* __restrict__ padadd) {
  const int t = threadIdx.x, l = t & 63, w = t >> 6;
  const size_t row = (size_t)blockIdx.x * 4 + w;
  u16x8 v = *(const u16x8*)(xe + row * 512 + l * 8);
  float s = 0.f;
  #pragma unroll
  for (int j = 0; j < 8; ++j) s += fabsf(b2f(v[j]));
  #pragma unroll
  for (int m = 1; m < 64; m <<= 1) s += __shfl_xor(s, m);
  if (l == 0) padadd[row] = (s == 0.f) ? -__builtin_inff() : 0.f;
}

// ---------------- attention weights per batch ----------------
__global__ __launch_bounds__(256) void att_kernel(const uint16_t* __restrict__ q,
                                                  const uint16_t* __restrict__ kk_,
                                                  const float* __restrict__ wts,
                                                  const float* __restrict__ padadd,
                                                  uint16_t* __restrict__ aw) {
  __shared__ uint16_t Qs[128 * 64];
  __shared__ uint16_t Ks[128 * 64];
  __shared__ float red[2][128];
  const int b = blockIdx.x;
  const int t = threadIdx.x, l = t & 63, w = t >> 6;
  const int wr = w >> 1, wc = w & 1, l15 = l & 15, hi = l >> 4;
  const int srow = t >> 3;         // 0..31
  const int schunk = (t & 7) * 8;  // 0..56
  const float SCALE = 0.088388347648318447f;  // 1/sqrt(128)

  float wv[4], pv[4];
  #pragma unroll
  for (int n = 0; n < 4; ++n) {
    int j = wc * 64 + n * 16 + l15;
    wv[n] = wts[(size_t)b * 128 + j];
    pv[n] = padadd[(size_t)b * 128 + j];
  }

  f32x4 awacc[4][4];
  #pragma unroll
  for (int m = 0; m < 4; ++m)
    #pragma unroll
    for (int n = 0; n < 4; ++n) awacc[m][n] = (f32x4){0.f, 0.f, 0.f, 0.f};

  for (int h = 0; h < 4; ++h) {
    f32x4 s[4][4];
    #pragma unroll
    for (int m = 0; m < 4; ++m)
      #pragma unroll
      for (int n = 0; n < 4; ++n) s[m][n] = (f32x4){0.f, 0.f, 0.f, 0.f};
    for (int half = 0; half < 2; ++half) {
      #pragma unroll
      for (int i = 0; i < 4; ++i) {
        const int r = i * 32 + srow;
        gld16(&Qs[r * 64 + schunk],
              q + (size_t)(b * 128 + r) * 512 + h * 128 + half * 64 + schunk);
        gld16(&Ks[r * 64 + schunk],
              kk_ + (size_t)(b * 128 + r) * 512 + h * 128 + half * 64 + schunk);
      }
      __syncthreads();
      #pragma unroll
      for (int ks = 0; ks < 2; ++ks) {
        const int k0 = ks * 32 + hi * 8;
        bf16x8 a[4], bb[4];
        #pragma unroll
        for (int m = 0; m < 4; ++m) a[m] = *(const bf16x8*)&Qs[(wr * 64 + m * 16 + l15) * 64 + k0];
        #pragma unroll
        for (int n = 0; n < 4; ++n) bb[n] = *(const bf16x8*)&Ks[(wc * 64 + n * 16 + l15) * 64 + k0];
        #pragma unroll
        for (int m = 0; m < 4; ++m)
          #pragma unroll
          for (int n = 0; n < 4; ++n) s[m][n] = MFMA16(a[m], bb[n], s[m][n]);
      }
      __syncthreads();
    }
    // exp (scores O(0.1): no max-subtraction; -inf pad -> exp = 0)
    #pragma unroll
    for (int m = 0; m < 4; ++m)
      #pragma unroll
      for (int n = 0; n < 4; ++n)
        #pragma unroll
        for (int r = 0; r < 4; ++r)
          s[m][n][r] = __expf(s[m][n][r] * SCALE + pv[n]);
    // per-head row sums -> red[wc][row]
    #pragma unroll
    for (int m = 0; m < 4; ++m)
      #pragma unroll
      for (int r = 0; r < 4; ++r) {
        float p = s[m][0][r] + s[m][1][r] + s[m][2][r] + s[m][3][r];
        p += __shfl_xor(p, 1); p += __shfl_xor(p, 2);
        p += __shfl_xor(p, 4); p += __shfl_xor(p, 8);
        if (l15 == 0) red[wc][wr * 64 + m * 16 + hi * 4 + r] = p;
      }
    __syncthreads();
    #pragma unroll
    for (int m = 0; m < 4; ++m)
      #pragma unroll
      for (int r = 0; r < 4; ++r) {
        const int row = wr * 64 + m * 16 + hi * 4 + r;
        const float zi = 1.f / (red[0][row] + red[1][row]);
        #pragma unroll
        for (int n = 0; n < 4; ++n) awacc[m][n][r] += s[m][n][r] * zi;
      }
    __syncthreads();
  }
  // multiply by key weights, renormalize each row, write bf16
  #pragma unroll
  for (int m = 0; m < 4; ++m)
    #pragma unroll
    for (int r = 0; r < 4; ++r) {
      float p = awacc[m][0][r] * wv[0] + awacc[m][1][r] * wv[1] +
                awacc[m][2][r] * wv[2] + awacc[m][3][r] * wv[3];
      p += __shfl_xor(p, 1); p += __shfl_xor(p, 2);
      p += __shfl_xor(p, 4); p += __shfl_xor(p, 8);
      if (l15 == 0) red[wc][wr * 64 + m * 16 + hi * 4 + r] = p;
    }
  __syncthreads();
  #pragma unroll
  for (int m = 0; m < 4; ++m)
    #pragma unroll
    for (int r = 0; r < 4; ++r) {
      const int row = wr * 64 + m * 16 + hi * 4 + r;
      const float zi = 1.f / (red[0][row] + red[1][row]);
      #pragma unroll
      for (int n = 0; n < 4; ++n) {
        const int col = wc * 64 + n * 16 + l15;
        aw[(size_t)b * 16384 + (size_t)row * 128 + col] = f2b(awacc[m][n][r] * wv[n] * zi);
      }
    }
}

// ---------------- h = LN(xe + softplus(O)) * g + b, one wave per row of 512 ----------------
__global__ __launch_bounds__(256) void lnh_kernel(const uint16_t* __restrict__ xe,
                                                  const uint16_t* __restrict__ O,
                                                  const float* __restrict__ g,
                                                  const float* __restrict__ be,
                                                  uint16_t* __restrict__ hout) {
  const int t = threadIdx.x, l = t & 63, w = t >> 6;
  const size_t row = (size_t)blockIdx.x * 4 + w;
  const size_t base = row * 512 + l * 8;
  u16x8 xv = *(const u16x8*)(xe + base);
  u16x8 ov = *(const u16x8*)(O + base);
  float hv[8];
  #pragma unroll
  for (int j = 0; j < 8; ++j) {
    float o = b2f(ov[j]);
    float sp = fmaxf(o, 0.f) + __logf(1.f + __expf(-fabsf(o)));
    hv[j] = b2f(xv[j]) + sp;
  }
  float s = 0.f;
  #pragma unroll
  for (int j = 0; j < 8; ++j) s += hv[j];
  #pragma unroll
  for (int m = 1; m < 64; m <<= 1) s += __shfl_xor(s, m);
  const float mu = s * (1.f / 512.f);
  float vs = 0.f;
  #pragma unroll
  for (int j = 0; j < 8; ++j) { float d = hv[j] - mu; vs += d * d; }
  #pragma unroll
  for (int m = 1; m < 64; m <<= 1) vs += __shfl_xor(vs, m);
  const float rstd = rsqrtf(vs * (1.f / 512.f) + 1e-5f);
  u16x8 outv;
  #pragma unroll
  for (int j = 0; j < 8; ++j) {
    const int c = l * 8 + j;
    outv[j] = f2b((hv[j] - mu) * rstd * g[c] + be[c]);
  }
  *(u16x8*)(hout + base) = outv;
}

// =======================================================================================
// Workspace budget (~205 MB peak) with buffer-reuse timeline:
//   B2: x_bf -> k -> O        B1: q -> vin -> h        aw lives in d_out[0:16.8MB]
extern "C" void kernel_launch(void* const* d_in, const int* in_sizes, int n_in,
                              void* d_out, int out_size, void* d_ws, size_t ws_size,
                              hipStream_t stream) {
  (void)in_sizes; (void)n_in; (void)out_size; (void)ws_size;
  const float* x     = (const float*)d_in[0];
  const float* wts   = (const float*)d_in[1];
  const float* emb_W = (const float*)d_in[2];
  const float* emb_b = (const float*)d_in[3];
  const float* wq_W  = (const float*)d_in[4];
  const float* wq_b  = (const float*)d_in[5];
  const float* wk_W  = (const float*)d_in[6];
  const float* wk_b  = (const float*)d_in[7];
  const float* wv_W  = (const float*)d_in[8];
  const float* wv_b  = (const float*)d_in[9];
  const float* ipW   = (const float*)d_in[10];
  const float* ipb   = (const float*)d_in[11];
  const float* ln_g  = (const float*)d_in[12];
  const float* ln_b  = (const float*)d_in[13];
  const float* out_W = (const float*)d_in[14];
  const float* out_b = (const float*)d_in[15];

  char* ws = (char*)d_ws;
  size_t off = 0;
  auto alloc = [&](size_t bytes) { void* p = ws + off; off += (bytes + 255) & ~(size_t)255; return p; };
  uint16_t* emb_bf = (uint16_t*)alloc(131072);
  uint16_t* wqW_bf = (uint16_t*)alloc(524288);
  uint16_t* wkW_bf = (uint16_t*)alloc(524288);
  uint16_t* wvW_bf = (uint16_t*)alloc(524288);
  uint16_t* ip_bf  = (uint16_t*)alloc(1048576);    // in_proj rows 0..1023 (Wq,Wk)
  uint16_t* owW_bf = (uint16_t*)alloc(131072);
  uint16_t* Wqc    = (uint16_t*)alloc(524288);
  uint16_t* Wkc    = (uint16_t*)alloc(524288);
  float*    bqc    = (float*)alloc(2048);
  float*    bkc    = (float*)alloc(2048);
  float*    pad    = (float*)alloc(262144);
  uint16_t* xe     = (uint16_t*)alloc(67108864);   // 65536 x 512 bf16, live to the end
  uint16_t* B1     = (uint16_t*)alloc(67108864);   // q -> vin -> h
  uint16_t* B2     = (uint16_t*)alloc(67108864);   // x_bf -> k -> O

  uint16_t* x_bf = B2;
  uint16_t* qb   = B1;
  uint16_t* kb   = B2;
  uint16_t* aw   = (uint16_t*)d_out;  // first 16.8MB of d_out; consumed before final GEMM
  uint16_t* vin  = B1;
  uint16_t* Ob   = B2;
  uint16_t* hb   = B1;

  const int TB = 256;
  // packs
  pack_bf16<<<8192, TB, 0, stream>>>(x, x_bf, 2097152);
  pack_bf16<<<64,   TB, 0, stream>>>(emb_W, emb_bf, 16384);
  pack_bf16<<<256,  TB, 0, stream>>>(wq_W, wqW_bf, 65536);
  pack_bf16<<<256,  TB, 0, stream>>>(wk_W, wkW_bf, 65536);
  pack_bf16<<<256,  TB, 0, stream>>>(wv_W, wvW_bf, 65536);
  pack_bf16<<<512,  TB, 0, stream>>>(ipW, ip_bf, 131072);
  pack_bf16<<<64,   TB, 0, stream>>>(out_W, owW_bf, 16384);
  // combined projection biases (f32): bqc = Wq@wq_b + bq ; bkc = Wk@wk_b + bk
  combine_bias<<<128, TB, 0, stream>>>(ipW, wq_b, ipb, bqc);
  combine_bias<<<128, TB, 0, stream>>>(ipW + 262144, wk_b, ipb + 512, bkc);
  // combined projection weights: Wqc = Wq @ wq_W ; Wkc = Wk @ wk_W   (512x512x512)
  gemm_ab_kernel<<<dim3(4, 4, 1), TB, 0, stream>>>(ip_bf, 512, 0, wqW_bf, 512, 0, Wqc, 512, 0, 512);
  gemm_ab_kernel<<<dim3(4, 4, 1), TB, 0, stream>>>(ip_bf + 262144, 512, 0, wkW_bf, 512, 0, Wkc, 512, 0, 512);
  // xe = x @ emb_W^T + emb_b   (65536 x 512, K=128)
  gemm_bt_kernel<uint16_t><<<dim3(4, 512), TB, 0, stream>>>(x_bf, emb_bf, emb_b, xe, 512, 128);
  pad_kernel<<<16384, TB, 0, stream>>>(xe, pad);
  // q = xe @ Wqc^T + bqc -> B1 ; k = xe @ Wkc^T + bkc -> B2 (x_bf dead)
  gemm_bt_kernel<uint16_t><<<dim3(4, 512), TB, 0, stream>>>(xe, Wqc, bqc, qb, 512, 512);
  gemm_bt_kernel<uint16_t><<<dim3(4, 512), TB, 0, stream>>>(xe, Wkc, bkc, kb, 512, 512);
  // attention weights -> aw (in d_out)
  att_kernel<<<512, TB, 0, stream>>>(qb, kb, wts, pad, aw);
  // v_in = xe @ wv^T + wv_b -> B1 (q dead)
  gemm_bt_kernel<uint16_t><<<dim3(4, 512), TB, 0, stream>>>(xe, wvW_bf, wv_b, vin, 512, 512);
  // att_output = aw @ v_in -> B2 (k dead)   (batched 128x512x128)
  gemm_ab_kernel<<<dim3(4, 1, 512), TB, 0, stream>>>(aw, 128, 16384, vin, 512, 65536,
                                                     Ob, 512, 65536, 128);
  // h = LN(xe + softplus(O)) -> B1 (vin dead)
  lnh_kernel<<<16384, TB, 0, stream>>>(xe, Ob, ln_g, ln_b, hb);
  // out = h @ out_W^T + out_b   (65536 x 128, K=512), f32 (overwrites aw region last)
  gemm_bt_kernel<float><<<dim3(1, 512), TB, 0, stream>>>(hb, owW_bf, out_b, (float*)d_out, 128, 512);
}

// Round 6
// 397.471 us; speedup vs baseline: 1.3803x; 1.1064x over previous
//
#include <hip/hip_runtime.h>
#include <stdint.h>

// Shapes (fixed): B=512, N=128, E=128, H=4, D=512, hd=128.

typedef __attribute__((ext_vector_type(8))) __bf16 bf16x8;
typedef __attribute__((ext_vector_type(8))) uint16_t u16x8;
typedef __attribute__((ext_vector_type(4))) float f32x4;

__device__ __forceinline__ float b2f(uint16_t h) {
  union { uint32_t u; float f; } c; c.u = ((uint32_t)h) << 16; return c.f;
}
__device__ __forceinline__ uint16_t f2b(float f) {
  union { float f; uint32_t u; } c; c.f = f;
  return (uint16_t)((c.u + 0x7fffu + ((c.u >> 16) & 1u)) >> 16);
}
__device__ __forceinline__ void gld16(void* lds, const void* g) {
  __builtin_amdgcn_global_load_lds(
      (const __attribute__((address_space(1))) uint32_t*)(g),
      (__attribute__((address_space(3))) uint32_t*)(lds),
      16, 0, 0);
}
__device__ __forceinline__ void stc(float* C, size_t i, float v) { C[i] = v; }
__device__ __forceinline__ void stc(uint16_t* C, size_t i, float v) { C[i] = f2b(v); }

#define MFMA16(a, b, c) __builtin_amdgcn_mfma_f32_16x16x32_bf16((a), (b), (c), 0, 0, 0)

// ---------------- pack f32 -> bf16 (4 elems/thread) ----------------
__global__ __launch_bounds__(256) void pack_bf16(const float* __restrict__ in,
                                                 uint16_t* __restrict__ out, int n4) {
  int i = blockIdx.x * 256 + threadIdx.x;
  if (i >= n4) return;
  float4 v = ((const float4*)in)[i];
  ushort4 o;
  o.x = f2b(v.x); o.y = f2b(v.y); o.z = f2b(v.z); o.w = f2b(v.w);
  ((ushort4*)out)[i] = o;
}

// ---------------- bqc[i] = b2[i] + sum_k Wbig[i,k]*b1[k]  (512x512, f32) ----------------
__global__ __launch_bounds__(256) void combine_bias(const float* __restrict__ Wbig,
                                                    const float* __restrict__ b1,
                                                    const float* __restrict__ b2,
                                                    float* __restrict__ out) {
  const int t = threadIdx.x, l = t & 63, w = t >> 6;
  const int row = blockIdx.x * 4 + w;
  float s = 0.f;
  #pragma unroll
  for (int j = 0; j < 8; ++j) {
    int c = j * 64 + l;
    s += Wbig[(size_t)row * 512 + c] * b1[c];
  }
  #pragma unroll
  for (int m = 1; m < 64; m <<= 1) s += __shfl_xor(s, m);
  if (l == 0) out[row] = s + b2[row];
}

// ---------------- C(MxN) = A(MxK) @ W(NxK)^T + bias ; 128x128 tile, BK=64 ----------------
// Double-buffered LDS, counted vmcnt(8), XCD-chunked swizzle, XOR bank-conflict swizzle
// (linear LDS dest + inverse-swizzled global source + swizzled ds_read — rule #21).
template <typename OT>
__global__ __launch_bounds__(256) void gemm_bt_kernel(
    const uint16_t* __restrict__ A, const uint16_t* __restrict__ W,
    const float* __restrict__ bias, OT* __restrict__ C, int N, int K) {
  __shared__ uint16_t As[2][128 * 64];
  __shared__ uint16_t Bs[2][128 * 64];
  const int t = threadIdx.x, l = t & 63, w = t >> 6;
  const int wr = w >> 1, wc = w & 1, l15 = l & 15, hi = l >> 4;
  // bijective XCD-chunk swizzle (nwg is a multiple of 8 for all our grids)
  const int gx = gridDim.x;
  const int nwg = gx * gridDim.y;
  const int lin = blockIdx.x + gx * blockIdx.y;
  const int cpx = nwg >> 3;
  const int sw = (lin & 7) * cpx + (lin >> 3);
  const int ntile = sw % gx, mtile = sw / gx;
  f32x4 acc[4][4];
  #pragma unroll
  for (int m = 0; m < 4; ++m)
    #pragma unroll
    for (int n = 0; n < 4; ++n) acc[m][n] = (f32x4){0.f, 0.f, 0.f, 0.f};
  const int srow = t >> 3;
  const int schunk = (t & 7) * 8;                       // linear LDS dest chunk
  const int gchunk = (((t & 7) ^ (srow & 7)) * 8);      // pre-swizzled global src chunk
  const int nk = K >> 6;
  const int rowA0 = mtile * 128, rowB0 = ntile * 128;
  auto stage = [&](int kt, int buf) {
    const int kb = kt << 6;
    #pragma unroll
    for (int i = 0; i < 4; ++i) {
      const int r = i * 32 + srow;
      gld16(&As[buf][r * 64 + schunk], A + (size_t)(rowA0 + r) * K + kb + gchunk);
      gld16(&Bs[buf][r * 64 + schunk], W + (size_t)(rowB0 + r) * K + kb + gchunk);
    }
  };
  stage(0, 0);
  const int rsw = (l15 & 7);  // read-side row-XOR (row & 7 == l15 & 7 for all frag rows)
  for (int kt = 0; kt < nk; ++kt) {
    const int cur = kt & 1;
    if (kt + 1 < nk) {
      stage(kt + 1, cur ^ 1);                                // next tile in flight
      asm volatile("s_waitcnt vmcnt(8)" ::: "memory");       // current tile's 8 done
    } else {
      asm volatile("s_waitcnt vmcnt(0)" ::: "memory");
    }
    __builtin_amdgcn_s_barrier();
    asm volatile("" ::: "memory");
    #pragma unroll
    for (int ks = 0; ks < 2; ++ks) {
      const int gck = ((ks * 4 + hi) ^ rsw) * 8;
      bf16x8 a[4], bb[4];
      #pragma unroll
      for (int m = 0; m < 4; ++m)
        a[m] = *(const bf16x8*)&As[cur][(wr * 64 + m * 16 + l15) * 64 + gck];
      #pragma unroll
      for (int n = 0; n < 4; ++n)
        bb[n] = *(const bf16x8*)&Bs[cur][(wc * 64 + n * 16 + l15) * 64 + gck];
      #pragma unroll
      for (int m = 0; m < 4; ++m)
        #pragma unroll
        for (int n = 0; n < 4; ++n) acc[m][n] = MFMA16(a[m], bb[n], acc[m][n]);
    }
    asm volatile("" ::: "memory");
    __builtin_amdgcn_s_barrier();
  }
  #pragma unroll
  for (int m = 0; m < 4; ++m) {
    const int row = rowA0 + wr * 64 + m * 16 + hi * 4;
    #pragma unroll
    for (int n = 0; n < 4; ++n) {
      const int col = rowB0 + wc * 64 + n * 16 + l15;
      const float bv = bias[col];
      #pragma unroll
      for (int r = 0; r < 4; ++r)
        stc(C, (size_t)(row + r) * N + col, acc[m][n][r] + bv);
    }
  }
}

// ---------------- C = A(MxK) @ B(KxN), B row-major (transpose-staged), bf16 out, batched ----
__global__ __launch_bounds__(256) void gemm_ab_kernel(
    const uint16_t* __restrict__ A, int lda, long long sA,
    const uint16_t* __restrict__ B, int ldb, long long sB,
    uint16_t* __restrict__ C, int ldc, long long sC, int K) {
  __shared__ uint16_t As[128 * 64];
  __shared__ uint16_t Bt[128 * 64];  // [n][k]
  const int t = threadIdx.x, l = t & 63, w = t >> 6;
  const int wr = w >> 1, wc = w & 1, l15 = l & 15, hi = l >> 4;
  const int gx = gridDim.x, gy = gridDim.y;
  const int nwg = gx * gy * gridDim.z;
  const int lin = blockIdx.x + gx * (blockIdx.y + gy * blockIdx.z);
  const int cpx = nwg >> 3;
  const int sw = (lin & 7) * cpx + (lin >> 3);
  const int ntile = sw % gx;
  const int rest = sw / gx;
  const int mtile = rest % gy, bz = rest / gy;
  const uint16_t* Ab = A + (size_t)bz * sA;
  const uint16_t* Bb = B + (size_t)bz * sB;
  uint16_t* Cb = C + (size_t)bz * sC;
  f32x4 acc[4][4];
  #pragma unroll
  for (int m = 0; m < 4; ++m)
    #pragma unroll
    for (int n = 0; n < 4; ++n) acc[m][n] = (f32x4){0.f, 0.f, 0.f, 0.f};
  const int srow = t >> 3, schunk = (t & 7) * 8;
  const int nk = K >> 6;
  for (int kt = 0; kt < nk; ++kt) {
    const int kb = kt << 6;
    #pragma unroll
    for (int i = 0; i < 4; ++i) {
      const int r = i * 32 + srow;
      gld16(&As[r * 64 + schunk], Ab + (size_t)(mtile * 128 + r) * lda + kb + schunk);
    }
    #pragma unroll
    for (int rd = 0; rd < 4; ++rd) {
      const int id = rd * 256 + t;
      const int kr = id >> 4;
      const int c = (id & 15) * 8;
      u16x8 gv = *(const u16x8*)(Bb + (size_t)(kb + kr) * ldb + ntile * 128 + c);
      #pragma unroll
      for (int j = 0; j < 8; ++j) Bt[(c + j) * 64 + kr] = gv[j];
    }
    __syncthreads();
    #pragma unroll
    for (int ks = 0; ks < 2; ++ks) {
      const int k0 = ks * 32 + hi * 8;
      bf16x8 a[4], bb[4];
      #pragma unroll
      for (int m = 0; m < 4; ++m) a[m] = *(const bf16x8*)&As[(wr * 64 + m * 16 + l15) * 64 + k0];
      #pragma unroll
      for (int n = 0; n < 4; ++n) bb[n] = *(const bf16x8*)&Bt[(wc * 64 + n * 16 + l15) * 64 + k0];
      #pragma unroll
      for (int m = 0; m < 4; ++m)
        #pragma unroll
        for (int n = 0; n < 4; ++n) acc[m][n] = MFMA16(a[m], bb[n], acc[m][n]);
    }
    __syncthreads();
  }
  #pragma unroll
  for (int m = 0; m < 4; ++m) {
    const int row = mtile * 128 + wr * 64 + m * 16 + hi * 4;
    #pragma unroll
    for (int n = 0; n < 4; ++n) {
      const int col = ntile * 128 + wc * 64 + n * 16 + l15;
      #pragma unroll
      for (int r = 0; r < 4; ++r)
        Cb[(size_t)(row + r) * ldc + col] = f2b(acc[m][n][r]);
    }
  }
}

// ---------------- pad flags: -inf where row of xe is all-zero ----------------
__global__ __launch_bounds__(256) void pad_kernel(const uint16_t* __restrict__ xe,
                                                  float* __restrict__ padadd) {
  const int t = threadIdx.x, l = t & 63, w = t >> 6;
  const size_t row = (size_t)blockIdx.x * 4 + w;
  u16x8 v = *(const u16x8*)(xe + row * 512 + l * 8);
  float s = 0.f;
  #pragma unroll
  for (int j = 0; j < 8; ++j) s += fabsf(b2f(v[j]));
  #pragma unroll
  for (int m = 1; m < 64; m <<= 1) s += __shfl_xor(s, m);
  if (l == 0) padadd[row] = (s == 0.f) ? -__builtin_inff() : 0.f;
}

// ---------------- attention weights per batch ----------------
// Wave-per-row-band (acc[2][8]: 32 rows x 128 cols per wave): all softmax reductions
// intra-wave (shfl), zero reduction barriers. Double-buffered Q/K staging, counted
// vmcnt(8), XOR bank-swizzle (linear LDS dest + swizzled global src + swizzled read).
__global__ __launch_bounds__(256) void att_kernel(const uint16_t* __restrict__ q,
                                                  const uint16_t* __restrict__ kk_,
                                                  const float* __restrict__ wts,
                                                  const float* __restrict__ padadd,
                                                  uint16_t* __restrict__ aw) {
  __shared__ uint16_t Qs[2][128 * 64];
  __shared__ uint16_t Ks[2][128 * 64];
  const int b = blockIdx.x;
  const int t = threadIdx.x, l = t & 63, wband = t >> 6;
  const int l15 = l & 15, hi = l >> 4;
  const int srow = t >> 3;
  const int schunk = (t & 7) * 8;                   // linear LDS dest
  const int gchunk = (((t & 7) ^ (srow & 7)) * 8);  // pre-swizzled global src
  const float SCALE = 0.088388347648318447f;        // 1/sqrt(128)

  float wv[8], pv[8];
  #pragma unroll
  for (int n = 0; n < 8; ++n) {
    const int j = n * 16 + l15;
    wv[n] = wts[(size_t)b * 128 + j];
    pv[n] = padadd[(size_t)b * 128 + j];
  }

  f32x4 awacc[2][8];
  #pragma unroll
  for (int m = 0; m < 2; ++m)
    #pragma unroll
    for (int n = 0; n < 8; ++n) awacc[m][n] = (f32x4){0.f, 0.f, 0.f, 0.f};

  auto stage = [&](int ph, int buf) {  // ph = h*2 + half
    const size_t colbase = (size_t)(ph >> 1) * 128 + (ph & 1) * 64;
    #pragma unroll
    for (int i = 0; i < 4; ++i) {
      const int r = i * 32 + srow;
      gld16(&Qs[buf][r * 64 + schunk], q + (size_t)(b * 128 + r) * 512 + colbase + gchunk);
      gld16(&Ks[buf][r * 64 + schunk], kk_ + (size_t)(b * 128 + r) * 512 + colbase + gchunk);
    }
  };

  const int rsw = (l15 & 7);
  f32x4 s[2][8];
  stage(0, 0);
  for (int ph = 0; ph < 8; ++ph) {
    const int cur = ph & 1;
    if ((ph & 1) == 0) {
      #pragma unroll
      for (int m = 0; m < 2; ++m)
        #pragma unroll
        for (int n = 0; n < 8; ++n) s[m][n] = (f32x4){0.f, 0.f, 0.f, 0.f};
    }
    if (ph + 1 < 8) {
      stage(ph + 1, cur ^ 1);
      asm volatile("s_waitcnt vmcnt(8)" ::: "memory");
    } else {
      asm volatile("s_waitcnt vmcnt(0)" ::: "memory");
    }
    __builtin_amdgcn_s_barrier();
    asm volatile("" ::: "memory");
    #pragma unroll
    for (int ks = 0; ks < 2; ++ks) {
      const int gck = ((ks * 4 + hi) ^ rsw) * 8;
      bf16x8 a[2], bb[8];
      #pragma unroll
      for (int m = 0; m < 2; ++m)
        a[m] = *(const bf16x8*)&Qs[cur][(wband * 32 + m * 16 + l15) * 64 + gck];
      #pragma unroll
      for (int n = 0; n < 8; ++n)
        bb[n] = *(const bf16x8*)&Ks[cur][(n * 16 + l15) * 64 + gck];
      #pragma unroll
      for (int m = 0; m < 2; ++m)
        #pragma unroll
        for (int n = 0; n < 8; ++n) s[m][n] = MFMA16(a[m], bb[n], s[m][n]);
    }
    asm volatile("" ::: "memory");
    __builtin_amdgcn_s_barrier();
    if ((ph & 1) == 1) {  // head complete: softmax + accumulate (register-only)
      #pragma unroll
      for (int m = 0; m < 2; ++m)
        #pragma unroll
        for (int r = 0; r < 4; ++r) {
          float e[8], z = 0.f;
          #pragma unroll
          for (int n = 0; n < 8; ++n) {
            e[n] = __expf(s[m][n][r] * SCALE + pv[n]);
            z += e[n];
          }
          z += __shfl_xor(z, 1); z += __shfl_xor(z, 2);
          z += __shfl_xor(z, 4); z += __shfl_xor(z, 8);
          const float zi = 1.f / z;
          #pragma unroll
          for (int n = 0; n < 8; ++n) awacc[m][n][r] += e[n] * zi;
        }
    }
  }
  // weight by w_j, renormalize each row (intra-wave), write bf16
  #pragma unroll
  for (int m = 0; m < 2; ++m)
    #pragma unroll
    for (int r = 0; r < 4; ++r) {
      float z = 0.f;
      #pragma unroll
      for (int n = 0; n < 8; ++n) z += awacc[m][n][r] * wv[n];
      z += __shfl_xor(z, 1); z += __shfl_xor(z, 2);
      z += __shfl_xor(z, 4); z += __shfl_xor(z, 8);
      const float zi = 1.f / z;
      const int row = wband * 32 + m * 16 + hi * 4 + r;
      #pragma unroll
      for (int n = 0; n < 8; ++n) {
        const int col = n * 16 + l15;
        aw[(size_t)b * 16384 + (size_t)row * 128 + col] = f2b(awacc[m][n][r] * wv[n] * zi);
      }
    }
}

// ---------------- h = LN(xe + softplus(O)) * g + b, one wave per row of 512 ----------------
__global__ __launch_bounds__(256) void lnh_kernel(const uint16_t* __restrict__ xe,
                                                  const uint16_t* __restrict__ O,
                                                  const float* __restrict__ g,
                                                  const float* __restrict__ be,
                                                  uint16_t* __restrict__ hout) {
  const int t = threadIdx.x, l = t & 63, w = t >> 6;
  const size_t row = (size_t)blockIdx.x * 4 + w;
  const size_t base = row * 512 + l * 8;
  u16x8 xv = *(const u16x8*)(xe + base);
  u16x8 ov = *(const u16x8*)(O + base);
  float hv[8];
  #pragma unroll
  for (int j = 0; j < 8; ++j) {
    float o = b2f(ov[j]);
    float sp = fmaxf(o, 0.f) + __logf(1.f + __expf(-fabsf(o)));
    hv[j] = b2f(xv[j]) + sp;
  }
  float s = 0.f;
  #pragma unroll
  for (int j = 0; j < 8; ++j) s += hv[j];
  #pragma unroll
  for (int m = 1; m < 64; m <<= 1) s += __shfl_xor(s, m);
  const float mu = s * (1.f / 512.f);
  float vs = 0.f;
  #pragma unroll
  for (int j = 0; j < 8; ++j) { float d = hv[j] - mu; vs += d * d; }
  #pragma unroll
  for (int m = 1; m < 64; m <<= 1) vs += __shfl_xor(vs, m);
  const float rstd = rsqrtf(vs * (1.f / 512.f) + 1e-5f);
  u16x8 outv;
  #pragma unroll
  for (int j = 0; j < 8; ++j) {
    const int c = l * 8 + j;
    outv[j] = f2b((hv[j] - mu) * rstd * g[c] + be[c]);
  }
  *(u16x8*)(hout + base) = outv;
}

// =======================================================================================
// Workspace budget (~205 MB peak) with buffer-reuse timeline:
//   B2: x_bf -> k -> O        B1: q -> vin -> h        aw lives in d_out[0:16.8MB]
extern "C" void kernel_launch(void* const* d_in, const int* in_sizes, int n_in,
                              void* d_out, int out_size, void* d_ws, size_t ws_size,
                              hipStream_t stream) {
  (void)in_sizes; (void)n_in; (void)out_size; (void)ws_size;
  const float* x     = (const float*)d_in[0];
  const float* wts   = (const float*)d_in[1];
  const float* emb_W = (const float*)d_in[2];
  const float* emb_b = (const float*)d_in[3];
  const float* wq_W  = (const float*)d_in[4];
  const float* wq_b  = (const float*)d_in[5];
  const float* wk_W  = (const float*)d_in[6];
  const float* wk_b  = (const float*)d_in[7];
  const float* wv_W  = (const float*)d_in[8];
  const float* wv_b  = (const float*)d_in[9];
  const float* ipW   = (const float*)d_in[10];
  const float* ipb   = (const float*)d_in[11];
  const float* ln_g  = (const float*)d_in[12];
  const float* ln_b  = (const float*)d_in[13];
  const float* out_W = (const float*)d_in[14];
  const float* out_b = (const float*)d_in[15];

  char* ws = (char*)d_ws;
  size_t off = 0;
  auto alloc = [&](size_t bytes) { void* p = ws + off; off += (bytes + 255) & ~(size_t)255; return p; };
  uint16_t* emb_bf = (uint16_t*)alloc(131072);
  uint16_t* wqW_bf = (uint16_t*)alloc(524288);
  uint16_t* wkW_bf = (uint16_t*)alloc(524288);
  uint16_t* wvW_bf = (uint16_t*)alloc(524288);
  uint16_t* ip_bf  = (uint16_t*)alloc(1048576);    // in_proj rows 0..1023 (Wq,Wk)
  uint16_t* owW_bf = (uint16_t*)alloc(131072);
  uint16_t* Wqc    = (uint16_t*)alloc(524288);
  uint16_t* Wkc    = (uint16_t*)alloc(524288);
  float*    bqc    = (float*)alloc(2048);
  float*    bkc    = (float*)alloc(2048);
  float*    pad    = (float*)alloc(262144);
  uint16_t* xe     = (uint16_t*)alloc(67108864);   // 65536 x 512 bf16, live to the end
  uint16_t* B1     = (uint16_t*)alloc(67108864);   // q -> vin -> h
  uint16_t* B2     = (uint16_t*)alloc(67108864);   // x_bf -> k -> O

  uint16_t* x_bf = B2;
  uint16_t* qb   = B1;
  uint16_t* kb   = B2;
  uint16_t* aw   = (uint16_t*)d_out;  // first 16.8MB of d_out; consumed before final GEMM
  uint16_t* vin  = B1;
  uint16_t* Ob   = B2;
  uint16_t* hb   = B1;

  const int TB = 256;
  // packs
  pack_bf16<<<8192, TB, 0, stream>>>(x, x_bf, 2097152);
  pack_bf16<<<64,   TB, 0, stream>>>(emb_W, emb_bf, 16384);
  pack_bf16<<<256,  TB, 0, stream>>>(wq_W, wqW_bf, 65536);
  pack_bf16<<<256,  TB, 0, stream>>>(wk_W, wkW_bf, 65536);
  pack_bf16<<<256,  TB, 0, stream>>>(wv_W, wvW_bf, 65536);
  pack_bf16<<<512,  TB, 0, stream>>>(ipW, ip_bf, 131072);
  pack_bf16<<<64,   TB, 0, stream>>>(out_W, owW_bf, 16384);
  // combined projection biases (f32): bqc = Wq@wq_b + bq ; bkc = Wk@wk_b + bk
  combine_bias<<<128, TB, 0, stream>>>(ipW, wq_b, ipb, bqc);
  combine_bias<<<128, TB, 0, stream>>>(ipW + 262144, wk_b, ipb + 512, bkc);
  // combined projection weights: Wqc = Wq @ wq_W ; Wkc = Wk @ wk_W   (512x512x512)
  gemm_ab_kernel<<<dim3(4, 4, 1), TB, 0, stream>>>(ip_bf, 512, 0, wqW_bf, 512, 0, Wqc, 512, 0, 512);
  gemm_ab_kernel<<<dim3(4, 4, 1), TB, 0, stream>>>(ip_bf + 262144, 512, 0, wkW_bf, 512, 0, Wkc, 512, 0, 512);
  // xe = x @ emb_W^T + emb_b   (65536 x 512, K=128)
  gemm_bt_kernel<uint16_t><<<dim3(4, 512), TB, 0, stream>>>(x_bf, emb_bf, emb_b, xe, 512, 128);
  pad_kernel<<<16384, TB, 0, stream>>>(xe, pad);
  // q = xe @ Wqc^T + bqc -> B1 ; k = xe @ Wkc^T + bkc -> B2 (x_bf dead)
  gemm_bt_kernel<uint16_t><<<dim3(4, 512), TB, 0, stream>>>(xe, Wqc, bqc, qb, 512, 512);
  gemm_bt_kernel<uint16_t><<<dim3(4, 512), TB, 0, stream>>>(xe, Wkc, bkc, kb, 512, 512);
  // attention weights -> aw (in d_out)
  att_kernel<<<512, TB, 0, stream>>>(qb, kb, wts, pad, aw);
  // v_in = xe @ wv^T + wv_b -> B1 (q dead)
  gemm_bt_kernel<uint16_t><<<dim3(4, 512), TB, 0, stream>>>(xe, wvW_bf, wv_b, vin, 512, 512);
  // att_output = aw @ v_in -> B2 (k dead)   (batched 128x512x128)
  gemm_ab_kernel<<<dim3(4, 1, 512), TB, 0, stream>>>(aw, 128, 16384, vin, 512, 65536,
                                                     Ob, 512, 65536, 128);
  // h = LN(xe + softplus(O)) -> B1 (vin dead)
  lnh_kernel<<<16384, TB, 0, stream>>>(xe, Ob, ln_g, ln_b, hb);
  // out = h @ out_W^T + out_b   (65536 x 128, K=512), f32 (overwrites aw region last)
  gemm_bt_kernel<float><<<dim3(1, 512), TB, 0, stream>>>(hb, owW_bf, out_b, (float*)d_out, 128, 512);
}